// Round 1
// baseline (1438.298 us; speedup 1.0000x reference)
//
#include <hip/hip_runtime.h>

typedef _Float16 h16;
typedef __attribute__((ext_vector_type(8))) _Float16 half8;
typedef __attribute__((ext_vector_type(4))) _Float16 half4;
typedef __attribute__((ext_vector_type(4))) float float4v;

#define NTOK  32400   // 5*60*108
#define NPTOK 720     // 5*12*12
#define CDIM  512
#define SCALE 0.08838834764831845f

// valid-index table for the rolled halo (nonzero of stacked tl,tr,bl,br 5x9 masks)
__constant__ int VIR_TBL[120] = {
  // part0 (tl): valid r>=3 || c>=5
  5,6,7,8, 14,15,16,17, 23,24,25,26,
  27,28,29,30,31,32,33,34,35, 36,37,38,39,40,41,42,43,44,
  // part1 (tr): valid r>=3 || c<4
  45,46,47,48, 54,55,56,57, 63,64,65,66,
  72,73,74,75,76,77,78,79,80, 81,82,83,84,85,86,87,88,89,
  // part2 (bl): valid r<2 || c>=5
  90,91,92,93,94,95,96,97,98, 99,100,101,102,103,104,105,106,107,
  113,114,115,116, 122,123,124,125, 131,132,133,134,
  // part3 (br): valid r<2 || c<4
  135,136,137,138,139,140,141,142,143, 144,145,146,147,148,149,150,151,152,
  153,154,155,156, 162,163,164,165, 171,172,173,174
};

// ---------------- GEMM 1: x0 @ W_qkv + b -> Q,K,V (fp16) ----------------
// M=32400, K=512, N=1536. 64x64 block tile, 256 thr, 4x4 microtile, fp32.
__global__ __launch_bounds__(256) void gemm_qkv(
    const float* __restrict__ A, const float* __restrict__ B,
    const float* __restrict__ bias,
    h16* __restrict__ Q, h16* __restrict__ K, h16* __restrict__ V)
{
  __shared__ float As[64][17];
  __shared__ float Bs[16][64];
  const int tid = threadIdx.x;
  const int bm = blockIdx.x, bn = blockIdx.y;
  const int tm = tid >> 4, tn = tid & 15;
  const int lrow = tid >> 2, lk = (tid & 3) * 4;
  const int brow = tid >> 4, bcol = (tid & 15) * 4;
  float acc[4][4] = {};
  const int arow = bm * 64 + lrow;
  const float* Ap = A + (size_t)arow * 512 + lk;
  const float* Bp = B + (size_t)brow * 1536 + bn * 64 + bcol;

  for (int k0 = 0; k0 < 512; k0 += 16) {
    float4 av = make_float4(0.f, 0.f, 0.f, 0.f);
    if (arow < NTOK) av = *(const float4*)(Ap + k0);
    float4 bv = *(const float4*)(Bp + (size_t)k0 * 1536);
    As[lrow][lk + 0] = av.x; As[lrow][lk + 1] = av.y;
    As[lrow][lk + 2] = av.z; As[lrow][lk + 3] = av.w;
    *(float4*)&Bs[brow][bcol] = bv;
    __syncthreads();
#pragma unroll
    for (int kk = 0; kk < 16; kk++) {
      float a[4];
#pragma unroll
      for (int i = 0; i < 4; i++) a[i] = As[tm * 4 + i][kk];
      float4 b = *(const float4*)&Bs[kk][tn * 4];
#pragma unroll
      for (int i = 0; i < 4; i++) {
        acc[i][0] = fmaf(a[i], b.x, acc[i][0]);
        acc[i][1] = fmaf(a[i], b.y, acc[i][1]);
        acc[i][2] = fmaf(a[i], b.z, acc[i][2]);
        acc[i][3] = fmaf(a[i], b.w, acc[i][3]);
      }
    }
    __syncthreads();
  }
  const int ng = bn * 64 + tn * 4;        // global col in [0,1536)
  const int j = ng >> 9;                   // 0->Q 1->K 2->V
  const int ch = ng & 511;
  h16* dst = (j == 0) ? Q : (j == 1) ? K : V;
#pragma unroll
  for (int i = 0; i < 4; i++) {
    int r = bm * 64 + tm * 4 + i;
    if (r < NTOK) {
#pragma unroll
      for (int c = 0; c < 4; c++)
        dst[(size_t)r * 512 + ch + c] = (h16)(acc[i][c] + bias[ng + c]);
    }
  }
}

// ---------------- GEMM 2: pooled x1 @ W_qkv[:,512:] -> Kp,Vp (fp16) ------
// out row = t*144 + py*12 + px ; src row in x1 = (py*12+px)*5 + t
__global__ __launch_bounds__(256) void gemm_pooled(
    const float* __restrict__ A, const float* __restrict__ B,
    const float* __restrict__ bias,
    h16* __restrict__ Kp, h16* __restrict__ Vp)
{
  __shared__ float As[64][17];
  __shared__ float Bs[16][64];
  const int tid = threadIdx.x;
  const int bm = blockIdx.x, bn = blockIdx.y;
  const int tm = tid >> 4, tn = tid & 15;
  const int lrow = tid >> 2, lk = (tid & 3) * 4;
  const int brow = tid >> 4, bcol = (tid & 15) * 4;
  float acc[4][4] = {};
  const int orow = bm * 64 + lrow;
  int srow = 0;
  if (orow < NPTOK) { int t = orow / 144, rem = orow % 144; srow = rem * 5 + t; }
  const float* Ap = A + (size_t)srow * 512 + lk;
  const float* Bp = B + (size_t)brow * 1536 + 512 + bn * 64 + bcol;

  for (int k0 = 0; k0 < 512; k0 += 16) {
    float4 av = make_float4(0.f, 0.f, 0.f, 0.f);
    if (orow < NPTOK) av = *(const float4*)(Ap + k0);
    float4 bv = *(const float4*)(Bp + (size_t)k0 * 1536);
    As[lrow][lk + 0] = av.x; As[lrow][lk + 1] = av.y;
    As[lrow][lk + 2] = av.z; As[lrow][lk + 3] = av.w;
    *(float4*)&Bs[brow][bcol] = bv;
    __syncthreads();
#pragma unroll
    for (int kk = 0; kk < 16; kk++) {
      float a[4];
#pragma unroll
      for (int i = 0; i < 4; i++) a[i] = As[tm * 4 + i][kk];
      float4 b = *(const float4*)&Bs[kk][tn * 4];
#pragma unroll
      for (int i = 0; i < 4; i++) {
        acc[i][0] = fmaf(a[i], b.x, acc[i][0]);
        acc[i][1] = fmaf(a[i], b.y, acc[i][1]);
        acc[i][2] = fmaf(a[i], b.z, acc[i][2]);
        acc[i][3] = fmaf(a[i], b.w, acc[i][3]);
      }
    }
    __syncthreads();
  }
  const int nl = bn * 64 + tn * 4;   // local col in [0,1024)
  const int j = nl >> 9;              // 0->Kp 1->Vp
  const int ch = nl & 511;
  h16* dst = (j == 0) ? Kp : Vp;
#pragma unroll
  for (int i = 0; i < 4; i++) {
    int r = bm * 64 + tm * 4 + i;
    if (r < NPTOK) {
#pragma unroll
      for (int c = 0; c < 4; c++)
        dst[(size_t)r * 512 + ch + c] = (h16)(acc[i][c] + bias[512 + nl + c]);
    }
  }
}

// ---------------- Attention: fp16 MFMA flash over gathered K/V ----------
// grid (144 win, 4 head, 4 qgroup), block 256 = 4 waves, wave owns 16 q rows.
__global__ __launch_bounds__(256) void attn_kernel(
    const h16* __restrict__ Qh, const h16* __restrict__ Kh,
    const h16* __restrict__ Vh, const h16* __restrict__ Kph,
    const h16* __restrict__ Vph, h16* __restrict__ AOh)
{
  __shared__ h16 Ks[32 * 136];
  __shared__ h16 Vs[32 * 136];
  __shared__ h16 Ps[4 * 16 * 40];
  __shared__ float biasLDS[32];

  const int tid = threadIdx.x;
  const int lane = tid & 63;
  const int wv = tid >> 6;
  const int win = blockIdx.x;
  const int head = blockIdx.y;
  const int qgroup = blockIdx.z;
  const int wy = win / 12, wx = win % 12;
  const int col = lane & 15;
  const int quad = lane >> 4;

  // ---- preload Q fragments (A-layout: row=col, k = dc*32 + quad*8 + j) ----
  const int qtile = qgroup * 4 + wv;
  const int qrow0 = qtile * 16 + col;
  half8 qfrag[4];
  if (qrow0 < 225) {
    int t = qrow0 / 45, pos = qrow0 % 45;
    int y = wy * 5 + pos / 9, x = wx * 9 + pos % 9;
    const h16* qsrc = Qh + (size_t)((t * 60 + y) * 108 + x) * CDIM + head * 128;
#pragma unroll
    for (int dc = 0; dc < 4; dc++)
      qfrag[dc] = *(const half8*)(qsrc + dc * 32 + quad * 8);
  } else {
#pragma unroll
    for (int dc = 0; dc < 4; dc++)
#pragma unroll
      for (int jj = 0; jj < 8; jj++) qfrag[dc][jj] = (h16)0.0f;
  }

  float4v O[8];
#pragma unroll
  for (int i = 0; i < 8; i++) O[i] = (float4v){0.f, 0.f, 0.f, 0.f};
  float m_run[4] = {-INFINITY, -INFINITY, -INFINITY, -INFINITY};
  float l_run[4] = {0.f, 0.f, 0.f, 0.f};

  const int grow = tid >> 3;   // gather row 0..31
  const int seg = tid & 7;
  const int cho = head * 128 + seg * 16;

  for (int step = 0; step < 33; ++step) {
    __syncthreads();
    // ---- gather K/V tile (32 rows) ----
    int kidx = step * 32 + grow;
    const h16* ksrc = nullptr;
    const h16* vsrc = nullptr;
    float bias = 0.f;
    if (kidx < 225) {
      int t = kidx / 45, pos = kidx % 45;
      int y = wy * 5 + pos / 9, x = wx * 9 + pos % 9;
      size_t tok = (size_t)((t * 60 + y) * 108 + x);
      ksrc = Kh + tok * CDIM; vsrc = Vh + tok * CDIM;
    } else if (kidx < 825) {
      int jj = kidx - 225;
      int t = jj / 120, m = jj % 120;
      int vir = VIR_TBL[m];
      int p = vir / 45, pos = vir % 45;
      int r = pos / 9, c = pos % 9;
      int sy = (p < 2) ? -2 : 2;
      int sx = (p & 1) ? 4 : -4;
      int y = (wy * 5 + r - sy + 60) % 60;
      int x = (wx * 9 + c - sx + 108) % 108;
      size_t tok = (size_t)((t * 60 + y) * 108 + x);
      ksrc = Kh + tok * CDIM; vsrc = Vh + tok * CDIM;
    } else if (kidx < 1050) {
      int jp = kidx - 825;
      int t = jp / 45, pos = jp % 45;
      int py = wy + pos / 9 - 2;
      int px = wx + pos % 9 - 4;
      if (py >= 0 && py < 12 && px >= 0 && px < 12) {
        size_t tok = (size_t)(t * 144 + py * 12 + px);
        ksrc = Kph + tok * CDIM; vsrc = Vph + tok * CDIM;
      } else bias = -100.f;   // zero K row + mask, exactly as reference
    } else {
      bias = -1e30f;          // pad rows of last tile
    }
    float4 kv0 = make_float4(0.f,0.f,0.f,0.f), kv1 = kv0, vv0 = kv0, vv1 = kv0;
    if (ksrc) {
      kv0 = *(const float4*)(ksrc + cho);
      kv1 = *(const float4*)(ksrc + cho + 8);
      vv0 = *(const float4*)(vsrc + cho);
      vv1 = *(const float4*)(vsrc + cho + 8);
    }
    *(float4*)&Ks[grow * 136 + seg * 16] = kv0;
    *(float4*)&Ks[grow * 136 + seg * 16 + 8] = kv1;
    *(float4*)&Vs[grow * 136 + seg * 16] = vv0;
    *(float4*)&Vs[grow * 136 + seg * 16 + 8] = vv1;
    if (seg == 0) biasLDS[grow] = bias;
    __syncthreads();

    // ---- S = Q K^T (two 16x16 tiles over the 32 k rows) ----
    float4v s0 = {0.f, 0.f, 0.f, 0.f}, s1 = {0.f, 0.f, 0.f, 0.f};
#pragma unroll
    for (int dc = 0; dc < 4; dc++) {
      half8 b0 = *(const half8*)&Ks[(col) * 136 + dc * 32 + quad * 8];
      half8 b1 = *(const half8*)&Ks[(col + 16) * 136 + dc * 32 + quad * 8];
      s0 = __builtin_amdgcn_mfma_f32_16x16x32_f16(qfrag[dc], b0, s0, 0, 0, 0);
      s1 = __builtin_amdgcn_mfma_f32_16x16x32_f16(qfrag[dc], b1, s1, 0, 0, 0);
    }

    // ---- online softmax (C-layout: row = quad*4+i, col = lane&15) ----
    float alpha[4], p0[4], p1[4];
#pragma unroll
    for (int i = 0; i < 4; i++) {
      float sa = s0[i] * SCALE + biasLDS[col];
      float sb = s1[i] * SCALE + biasLDS[col + 16];
      float mx = fmaxf(sa, sb);
      mx = fmaxf(mx, __shfl_xor(mx, 1));
      mx = fmaxf(mx, __shfl_xor(mx, 2));
      mx = fmaxf(mx, __shfl_xor(mx, 4));
      mx = fmaxf(mx, __shfl_xor(mx, 8));
      float mn = fmaxf(m_run[i], mx);
      alpha[i] = __expf(m_run[i] - mn);
      p0[i] = __expf(sa - mn);
      p1[i] = __expf(sb - mn);
      float rs = p0[i] + p1[i];
      rs += __shfl_xor(rs, 1);
      rs += __shfl_xor(rs, 2);
      rs += __shfl_xor(rs, 4);
      rs += __shfl_xor(rs, 8);
      l_run[i] = l_run[i] * alpha[i] + rs;
      m_run[i] = mn;
    }
#pragma unroll
    for (int dt = 0; dt < 8; dt++)
#pragma unroll
      for (int i = 0; i < 4; i++) O[dt][i] *= alpha[i];

    // ---- P -> LDS (convert to A-layout), then O += P V ----
    h16* Pw = &Ps[wv * 16 * 40];
#pragma unroll
    for (int i = 0; i < 4; i++) {
      int qr = quad * 4 + i;
      Pw[qr * 40 + col] = (h16)p0[i];
      Pw[qr * 40 + col + 16] = (h16)p1[i];
    }
    half8 pfrag = *(const half8*)&Pw[col * 40 + quad * 8];
#pragma unroll
    for (int dt = 0; dt < 8; dt++) {
      half8 vf;
#pragma unroll
      for (int j = 0; j < 8; j++)
        vf[j] = Vs[(quad * 8 + j) * 136 + dt * 16 + col];
      O[dt] = __builtin_amdgcn_mfma_f32_16x16x32_f16(pfrag, vf, O[dt], 0, 0, 0);
    }
  }

  // ---- epilogue ----
  float invl[4];
#pragma unroll
  for (int i = 0; i < 4; i++) invl[i] = 1.f / l_run[i];
#pragma unroll
  for (int i = 0; i < 4; i++) {
    int qr = qtile * 16 + quad * 4 + i;
    if (qr < 225) {
      h16* dst = AOh + ((size_t)win * 225 + qr) * CDIM + head * 128 + col;
#pragma unroll
      for (int dt = 0; dt < 8; dt++)
        dst[dt * 16] = (h16)(O[dt][i] * invl[i]);
    }
  }
}

// ---------------- GEMM 3: AO(fp16) @ W_proj + b -> out (fp32) -----------
__global__ __launch_bounds__(256) void gemm_proj(
    const h16* __restrict__ A, const float* __restrict__ B,
    const float* __restrict__ bias, float* __restrict__ out)
{
  __shared__ float As[64][17];
  __shared__ float Bs[16][64];
  const int tid = threadIdx.x;
  const int bm = blockIdx.x, bn = blockIdx.y;
  const int tm = tid >> 4, tn = tid & 15;
  const int lrow = tid >> 2, lk = (tid & 3) * 4;
  const int brow = tid >> 4, bcol = (tid & 15) * 4;
  float acc[4][4] = {};
  const int arow = bm * 64 + lrow;
  const h16* Ap = A + (size_t)arow * 512 + lk;
  const float* Bp = B + (size_t)brow * 512 + bn * 64 + bcol;

  for (int k0 = 0; k0 < 512; k0 += 16) {
    float4 av = make_float4(0.f, 0.f, 0.f, 0.f);
    if (arow < NTOK) {
      half4 hv = *(const half4*)(Ap + k0);
      av.x = (float)hv[0]; av.y = (float)hv[1];
      av.z = (float)hv[2]; av.w = (float)hv[3];
    }
    float4 bv = *(const float4*)(Bp + (size_t)k0 * 512);
    As[lrow][lk + 0] = av.x; As[lrow][lk + 1] = av.y;
    As[lrow][lk + 2] = av.z; As[lrow][lk + 3] = av.w;
    *(float4*)&Bs[brow][bcol] = bv;
    __syncthreads();
#pragma unroll
    for (int kk = 0; kk < 16; kk++) {
      float a[4];
#pragma unroll
      for (int i = 0; i < 4; i++) a[i] = As[tm * 4 + i][kk];
      float4 b = *(const float4*)&Bs[kk][tn * 4];
#pragma unroll
      for (int i = 0; i < 4; i++) {
        acc[i][0] = fmaf(a[i], b.x, acc[i][0]);
        acc[i][1] = fmaf(a[i], b.y, acc[i][1]);
        acc[i][2] = fmaf(a[i], b.z, acc[i][2]);
        acc[i][3] = fmaf(a[i], b.w, acc[i][3]);
      }
    }
    __syncthreads();
  }
  const int ng = bn * 64 + tn * 4;
#pragma unroll
  for (int i = 0; i < 4; i++) {
    int r = bm * 64 + tm * 4 + i;
    if (r < NTOK) {
#pragma unroll
      for (int c = 0; c < 4; c++)
        out[(size_t)r * 512 + ng + c] = acc[i][c] + bias[ng + c];
    }
  }
}

extern "C" void kernel_launch(void* const* d_in, const int* in_sizes, int n_in,
                              void* d_out, int out_size, void* d_ws, size_t ws_size,
                              hipStream_t stream) {
  const float* x0    = (const float*)d_in[0];
  const float* x1    = (const float*)d_in[1];
  const float* Wqkv  = (const float*)d_in[2];
  const float* bqkv  = (const float*)d_in[3];
  const float* Wproj = (const float*)d_in[4];
  const float* bproj = (const float*)d_in[5];
  float* out = (float*)d_out;

  h16* Qh  = (h16*)d_ws;
  h16* Kh  = Qh + (size_t)NTOK * CDIM;
  h16* Vh  = Kh + (size_t)NTOK * CDIM;
  h16* AOh = Vh + (size_t)NTOK * CDIM;
  h16* Kph = AOh + (size_t)NTOK * CDIM;
  h16* Vph = Kph + (size_t)NPTOK * CDIM;

  gemm_qkv<<<dim3(507, 24), 256, 0, stream>>>(x0, Wqkv, bqkv, Qh, Kh, Vh);
  gemm_pooled<<<dim3(12, 16), 256, 0, stream>>>(x1, Wqkv, bqkv, Kph, Vph);
  attn_kernel<<<dim3(144, 4, 4), 256, 0, stream>>>(Qh, Kh, Vh, Kph, Vph, AOh);
  gemm_proj<<<dim3(507, 8), 256, 0, stream>>>(AOh, Wproj, bproj, out);
}

// Round 2
// 678.866 us; speedup vs baseline: 2.1187x; 2.1187x over previous
//
#include <hip/hip_runtime.h>

typedef _Float16 h16;
typedef __attribute__((ext_vector_type(8))) _Float16 half8;
typedef __attribute__((ext_vector_type(4))) _Float16 half4;
typedef __attribute__((ext_vector_type(4))) float float4v;

#define NTOK  32400   // 5*60*108  (== 144 windows * 225 rows, too)
#define NPTOK 720     // 5*12*12
#define CDIM  512
#define SCALE 0.08838834764831845f

// valid-index table for the rolled halo (nonzero of stacked tl,tr,bl,br 5x9 masks)
__constant__ int VIR_TBL[120] = {
  5,6,7,8, 14,15,16,17, 23,24,25,26,
  27,28,29,30,31,32,33,34,35, 36,37,38,39,40,41,42,43,44,
  45,46,47,48, 54,55,56,57, 63,64,65,66,
  72,73,74,75,76,77,78,79,80, 81,82,83,84,85,86,87,88,89,
  90,91,92,93,94,95,96,97,98, 99,100,101,102,103,104,105,106,107,
  113,114,115,116, 122,123,124,125, 131,132,133,134,
  135,136,137,138,139,140,141,142,143, 144,145,146,147,148,149,150,151,152,
  153,154,155,156, 162,163,164,165, 171,172,173,174
};

// ---------------- cvt_x0: fp32 -> f16 elementwise (float4 -> half4) ------
__global__ __launch_bounds__(256) void cvt_x0(const float* __restrict__ src,
                                              h16* __restrict__ dst) {
  int idx = blockIdx.x * 256 + threadIdx.x;   // one float4 per thread
  float4 v = *(const float4*)(src + (size_t)idx * 4);
  half4 h;
  h[0] = (h16)v.x; h[1] = (h16)v.y; h[2] = (h16)v.z; h[3] = (h16)v.w;
  *(half4*)(dst + (size_t)idx * 4) = h;
}

// ------------- transpose_cvt: src R x C fp32 -> dst C x R f16 ------------
__global__ __launch_bounds__(256) void transpose_cvt(const float* __restrict__ src,
                                                     h16* __restrict__ dst,
                                                     int R, int C) {
  __shared__ float T[32][33];
  const int t = threadIdx.x;
  const int ct = blockIdx.x * 32;   // col (n) tile in src
  const int rt = blockIdx.y * 32;   // row (k) tile in src
  const int c = t & 31, r0 = (t >> 5) * 4;
#pragma unroll
  for (int i = 0; i < 4; i++)
    T[r0 + i][c] = src[(size_t)(rt + r0 + i) * C + ct + c];
  __syncthreads();
#pragma unroll
  for (int i = 0; i < 4; i++)
    dst[(size_t)(ct + r0 + i) * R + rt + c] = (h16)T[c][r0 + i];
}

// ---------------- MFMA GEMM core (shared LDS shapes) ---------------------
struct StageLDS { h16 Ah[128][40]; h16 Bh[128][40]; };
union GemmLDS { StageLDS s; h16 Cs[128][136]; };

// GEMM 1: X0h(32400x512 f16) @ Wqkvt^T + b -> Q,K,V (f16)
// Bt layout: [n][k] (1536 x 512). Block tile 128x128, 4 waves of 64x64.
__global__ __launch_bounds__(256) void gemm_qkv_mfma(
    const h16* __restrict__ A, const h16* __restrict__ Bt,
    const float* __restrict__ bias,
    h16* __restrict__ Q, h16* __restrict__ K, h16* __restrict__ V)
{
  __shared__ GemmLDS u;
  const int tid = threadIdx.x;
  const int lane = tid & 63, wv = tid >> 6;
  const int col = lane & 15, quad = lane >> 4;
  const int bm = blockIdx.x, bn = blockIdx.y;
  const int mo = (wv & 1) * 64, no = (wv >> 1) * 64;

  float4v acc[4][4];
#pragma unroll
  for (int i = 0; i < 4; i++)
#pragma unroll
    for (int j = 0; j < 4; j++) acc[i][j] = (float4v){0.f, 0.f, 0.f, 0.f};

  const int srow = tid >> 1, skoff = (tid & 1) * 16;
  const int arow = bm * 128 + srow;
  const h16* Ap = A + (size_t)arow * 512 + skoff;
  const h16* Bp = Bt + (size_t)(bn * 128 + srow) * 512 + skoff;

  for (int k0 = 0; k0 < 512; k0 += 32) {
    half8 a0, a1, b0, b1;
    if (arow < NTOK) {
      a0 = *(const half8*)(Ap + k0);
      a1 = *(const half8*)(Ap + k0 + 8);
    } else {
#pragma unroll
      for (int jj = 0; jj < 8; jj++) { a0[jj] = (h16)0.f; a1[jj] = (h16)0.f; }
    }
    b0 = *(const half8*)(Bp + k0);
    b1 = *(const half8*)(Bp + k0 + 8);
    __syncthreads();
    *(half8*)&u.s.Ah[srow][skoff] = a0;
    *(half8*)&u.s.Ah[srow][skoff + 8] = a1;
    *(half8*)&u.s.Bh[srow][skoff] = b0;
    *(half8*)&u.s.Bh[srow][skoff + 8] = b1;
    __syncthreads();

    half8 afr[4], bfr[4];
#pragma unroll
    for (int i = 0; i < 4; i++)
      afr[i] = *(const half8*)&u.s.Ah[mo + i * 16 + col][quad * 8];
#pragma unroll
    for (int j = 0; j < 4; j++)
      bfr[j] = *(const half8*)&u.s.Bh[no + j * 16 + col][quad * 8];
#pragma unroll
    for (int i = 0; i < 4; i++)
#pragma unroll
      for (int j = 0; j < 4; j++)
        acc[i][j] = __builtin_amdgcn_mfma_f32_16x16x32_f16(afr[i], bfr[j], acc[i][j], 0, 0, 0);
  }

  // epilogue: bias + repack via LDS for coalesced half8 stores
  __syncthreads();
  float bv[4];
#pragma unroll
  for (int j = 0; j < 4; j++) bv[j] = bias[bn * 128 + no + j * 16 + col];
#pragma unroll
  for (int i = 0; i < 4; i++)
#pragma unroll
    for (int j = 0; j < 4; j++)
#pragma unroll
      for (int r = 0; r < 4; r++)
        u.Cs[mo + i * 16 + quad * 4 + r][no + j * 16 + col] = (h16)(acc[i][j][r] + bv[j]);
  __syncthreads();

  const int row_l = tid >> 1, halfseg = (tid & 1) * 64;
  const int row_g = bm * 128 + row_l;
  const int jsel = bn >> 2;                  // 0->Q 1->K 2->V (whole block uniform)
  const int ch0 = (bn & 3) * 128 + halfseg;
  h16* dst = (jsel == 0) ? Q : (jsel == 1) ? K : V;
  if (row_g < NTOK) {
#pragma unroll
    for (int c = 0; c < 64; c += 8)
      *(half8*)&dst[(size_t)row_g * 512 + ch0 + c] = *(const half8*)&u.Cs[row_l][halfseg + c];
  }
}

// GEMM 3: AO(32400x512 f16) @ Wprojt^T + b -> out (fp32)
__global__ __launch_bounds__(256) void gemm_proj_mfma(
    const h16* __restrict__ A, const h16* __restrict__ Bt,
    const float* __restrict__ bias, float* __restrict__ out)
{
  __shared__ StageLDS s;
  const int tid = threadIdx.x;
  const int lane = tid & 63, wv = tid >> 6;
  const int col = lane & 15, quad = lane >> 4;
  const int bm = blockIdx.x, bn = blockIdx.y;
  const int mo = (wv & 1) * 64, no = (wv >> 1) * 64;

  float4v acc[4][4];
#pragma unroll
  for (int i = 0; i < 4; i++)
#pragma unroll
    for (int j = 0; j < 4; j++) acc[i][j] = (float4v){0.f, 0.f, 0.f, 0.f};

  const int srow = tid >> 1, skoff = (tid & 1) * 16;
  const int arow = bm * 128 + srow;
  const h16* Ap = A + (size_t)arow * 512 + skoff;
  const h16* Bp = Bt + (size_t)(bn * 128 + srow) * 512 + skoff;

  for (int k0 = 0; k0 < 512; k0 += 32) {
    half8 a0, a1, b0, b1;
    if (arow < NTOK) {
      a0 = *(const half8*)(Ap + k0);
      a1 = *(const half8*)(Ap + k0 + 8);
    } else {
#pragma unroll
      for (int jj = 0; jj < 8; jj++) { a0[jj] = (h16)0.f; a1[jj] = (h16)0.f; }
    }
    b0 = *(const half8*)(Bp + k0);
    b1 = *(const half8*)(Bp + k0 + 8);
    __syncthreads();
    *(half8*)&s.Ah[srow][skoff] = a0;
    *(half8*)&s.Ah[srow][skoff + 8] = a1;
    *(half8*)&s.Bh[srow][skoff] = b0;
    *(half8*)&s.Bh[srow][skoff + 8] = b1;
    __syncthreads();

    half8 afr[4], bfr[4];
#pragma unroll
    for (int i = 0; i < 4; i++)
      afr[i] = *(const half8*)&s.Ah[mo + i * 16 + col][quad * 8];
#pragma unroll
    for (int j = 0; j < 4; j++)
      bfr[j] = *(const half8*)&s.Bh[no + j * 16 + col][quad * 8];
#pragma unroll
    for (int i = 0; i < 4; i++)
#pragma unroll
      for (int j = 0; j < 4; j++)
        acc[i][j] = __builtin_amdgcn_mfma_f32_16x16x32_f16(afr[i], bfr[j], acc[i][j], 0, 0, 0);
  }

  float bv[4];
#pragma unroll
  for (int j = 0; j < 4; j++) bv[j] = bias[bn * 128 + no + j * 16 + col];
#pragma unroll
  for (int i = 0; i < 4; i++) {
#pragma unroll
    for (int r = 0; r < 4; r++) {
      int row_g = bm * 128 + mo + i * 16 + quad * 4 + r;
      if (row_g < NTOK) {
#pragma unroll
        for (int j = 0; j < 4; j++)
          out[(size_t)row_g * 512 + bn * 128 + no + j * 16 + col] = acc[i][j][r] + bv[j];
      }
    }
  }
}

// ---------------- GEMM 2: pooled x1 @ W_qkv[:,512:] -> Kp,Vp (fp16) ------
__global__ __launch_bounds__(256) void gemm_pooled(
    const float* __restrict__ A, const float* __restrict__ B,
    const float* __restrict__ bias,
    h16* __restrict__ Kp, h16* __restrict__ Vp)
{
  __shared__ float As[64][17];
  __shared__ float Bs[16][64];
  const int tid = threadIdx.x;
  const int bm = blockIdx.x, bn = blockIdx.y;
  const int tm = tid >> 4, tn = tid & 15;
  const int lrow = tid >> 2, lk = (tid & 3) * 4;
  const int brow = tid >> 4, bcol = (tid & 15) * 4;
  float acc[4][4] = {};
  const int orow = bm * 64 + lrow;
  int srow = 0;
  if (orow < NPTOK) { int t = orow / 144, rem = orow % 144; srow = rem * 5 + t; }
  const float* Ap = A + (size_t)srow * 512 + lk;
  const float* Bp = B + (size_t)brow * 1536 + 512 + bn * 64 + bcol;

  for (int k0 = 0; k0 < 512; k0 += 16) {
    float4 av = make_float4(0.f, 0.f, 0.f, 0.f);
    if (orow < NPTOK) av = *(const float4*)(Ap + k0);
    float4 bv = *(const float4*)(Bp + (size_t)k0 * 1536);
    As[lrow][lk + 0] = av.x; As[lrow][lk + 1] = av.y;
    As[lrow][lk + 2] = av.z; As[lrow][lk + 3] = av.w;
    *(float4*)&Bs[brow][bcol] = bv;
    __syncthreads();
#pragma unroll
    for (int kk = 0; kk < 16; kk++) {
      float a[4];
#pragma unroll
      for (int i = 0; i < 4; i++) a[i] = As[tm * 4 + i][kk];
      float4 b = *(const float4*)&Bs[kk][tn * 4];
#pragma unroll
      for (int i = 0; i < 4; i++) {
        acc[i][0] = fmaf(a[i], b.x, acc[i][0]);
        acc[i][1] = fmaf(a[i], b.y, acc[i][1]);
        acc[i][2] = fmaf(a[i], b.z, acc[i][2]);
        acc[i][3] = fmaf(a[i], b.w, acc[i][3]);
      }
    }
    __syncthreads();
  }
  const int nl = bn * 64 + tn * 4;   // local col in [0,1024)
  const int j = nl >> 9;              // 0->Kp 1->Vp
  const int ch = nl & 511;
  h16* dst = (j == 0) ? Kp : Vp;
#pragma unroll
  for (int i = 0; i < 4; i++) {
    int r = bm * 64 + tm * 4 + i;
    if (r < NPTOK) {
#pragma unroll
      for (int c = 0; c < 4; c++)
        dst[(size_t)r * 512 + ch + c] = (h16)(acc[i][c] + bias[512 + nl + c]);
    }
  }
}

// ---------------- Attention: fp16 MFMA flash over gathered K/V ----------
__global__ __launch_bounds__(256) void attn_kernel(
    const h16* __restrict__ Qh, const h16* __restrict__ Kh,
    const h16* __restrict__ Vh, const h16* __restrict__ Kph,
    const h16* __restrict__ Vph, h16* __restrict__ AOh)
{
  __shared__ h16 Ks[32 * 136];
  __shared__ h16 Vs[32 * 136];
  __shared__ h16 Ps[4 * 16 * 40];
  __shared__ float biasLDS[32];

  const int tid = threadIdx.x;
  const int lane = tid & 63;
  const int wv = tid >> 6;
  const int win = blockIdx.x;
  const int head = blockIdx.y;
  const int qgroup = blockIdx.z;
  const int wy = win / 12, wx = win % 12;
  const int col = lane & 15;
  const int quad = lane >> 4;

  const int qtile = qgroup * 4 + wv;
  const int qrow0 = qtile * 16 + col;
  half8 qfrag[4];
  if (qrow0 < 225) {
    int t = qrow0 / 45, pos = qrow0 % 45;
    int y = wy * 5 + pos / 9, x = wx * 9 + pos % 9;
    const h16* qsrc = Qh + (size_t)((t * 60 + y) * 108 + x) * CDIM + head * 128;
#pragma unroll
    for (int dc = 0; dc < 4; dc++)
      qfrag[dc] = *(const half8*)(qsrc + dc * 32 + quad * 8);
  } else {
#pragma unroll
    for (int dc = 0; dc < 4; dc++)
#pragma unroll
      for (int jj = 0; jj < 8; jj++) qfrag[dc][jj] = (h16)0.0f;
  }

  float4v O[8];
#pragma unroll
  for (int i = 0; i < 8; i++) O[i] = (float4v){0.f, 0.f, 0.f, 0.f};
  float m_run[4] = {-INFINITY, -INFINITY, -INFINITY, -INFINITY};
  float l_run[4] = {0.f, 0.f, 0.f, 0.f};

  const int grow = tid >> 3;
  const int seg = tid & 7;
  const int cho = head * 128 + seg * 16;

  for (int step = 0; step < 33; ++step) {
    __syncthreads();
    int kidx = step * 32 + grow;
    const h16* ksrc = nullptr;
    const h16* vsrc = nullptr;
    float bias = 0.f;
    if (kidx < 225) {
      int t = kidx / 45, pos = kidx % 45;
      int y = wy * 5 + pos / 9, x = wx * 9 + pos % 9;
      size_t tok = (size_t)((t * 60 + y) * 108 + x);
      ksrc = Kh + tok * CDIM; vsrc = Vh + tok * CDIM;
    } else if (kidx < 825) {
      int jj = kidx - 225;
      int t = jj / 120, m = jj % 120;
      int vir = VIR_TBL[m];
      int p = vir / 45, pos = vir % 45;
      int r = pos / 9, c = pos % 9;
      int sy = (p < 2) ? -2 : 2;
      int sx = (p & 1) ? 4 : -4;
      int y = (wy * 5 + r - sy + 60) % 60;
      int x = (wx * 9 + c - sx + 108) % 108;
      size_t tok = (size_t)((t * 60 + y) * 108 + x);
      ksrc = Kh + tok * CDIM; vsrc = Vh + tok * CDIM;
    } else if (kidx < 1050) {
      int jp = kidx - 825;
      int t = jp / 45, pos = jp % 45;
      int py = wy + pos / 9 - 2;
      int px = wx + pos % 9 - 4;
      if (py >= 0 && py < 12 && px >= 0 && px < 12) {
        size_t tok = (size_t)(t * 144 + py * 12 + px);
        ksrc = Kph + tok * CDIM; vsrc = Vph + tok * CDIM;
      } else bias = -100.f;
    } else {
      bias = -1e30f;
    }
    float4 kv0 = make_float4(0.f,0.f,0.f,0.f), kv1 = kv0, vv0 = kv0, vv1 = kv0;
    if (ksrc) {
      kv0 = *(const float4*)(ksrc + cho);
      kv1 = *(const float4*)(ksrc + cho + 8);
      vv0 = *(const float4*)(vsrc + cho);
      vv1 = *(const float4*)(vsrc + cho + 8);
    }
    *(float4*)&Ks[grow * 136 + seg * 16] = kv0;
    *(float4*)&Ks[grow * 136 + seg * 16 + 8] = kv1;
    *(float4*)&Vs[grow * 136 + seg * 16] = vv0;
    *(float4*)&Vs[grow * 136 + seg * 16 + 8] = vv1;
    if (seg == 0) biasLDS[grow] = bias;
    __syncthreads();

    float4v s0 = {0.f, 0.f, 0.f, 0.f}, s1 = {0.f, 0.f, 0.f, 0.f};
#pragma unroll
    for (int dc = 0; dc < 4; dc++) {
      half8 b0 = *(const half8*)&Ks[(col) * 136 + dc * 32 + quad * 8];
      half8 b1 = *(const half8*)&Ks[(col + 16) * 136 + dc * 32 + quad * 8];
      s0 = __builtin_amdgcn_mfma_f32_16x16x32_f16(qfrag[dc], b0, s0, 0, 0, 0);
      s1 = __builtin_amdgcn_mfma_f32_16x16x32_f16(qfrag[dc], b1, s1, 0, 0, 0);
    }

    float alpha[4], p0[4], p1[4];
#pragma unroll
    for (int i = 0; i < 4; i++) {
      float sa = s0[i] * SCALE + biasLDS[col];
      float sb = s1[i] * SCALE + biasLDS[col + 16];
      float mx = fmaxf(sa, sb);
      mx = fmaxf(mx, __shfl_xor(mx, 1));
      mx = fmaxf(mx, __shfl_xor(mx, 2));
      mx = fmaxf(mx, __shfl_xor(mx, 4));
      mx = fmaxf(mx, __shfl_xor(mx, 8));
      float mn = fmaxf(m_run[i], mx);
      alpha[i] = __expf(m_run[i] - mn);
      p0[i] = __expf(sa - mn);
      p1[i] = __expf(sb - mn);
      float rs = p0[i] + p1[i];
      rs += __shfl_xor(rs, 1);
      rs += __shfl_xor(rs, 2);
      rs += __shfl_xor(rs, 4);
      rs += __shfl_xor(rs, 8);
      l_run[i] = l_run[i] * alpha[i] + rs;
      m_run[i] = mn;
    }
#pragma unroll
    for (int dt = 0; dt < 8; dt++)
#pragma unroll
      for (int i = 0; i < 4; i++) O[dt][i] *= alpha[i];

    h16* Pw = &Ps[wv * 16 * 40];
#pragma unroll
    for (int i = 0; i < 4; i++) {
      int qr = quad * 4 + i;
      Pw[qr * 40 + col] = (h16)p0[i];
      Pw[qr * 40 + col + 16] = (h16)p1[i];
    }
    half8 pfrag = *(const half8*)&Pw[col * 40 + quad * 8];
#pragma unroll
    for (int dt = 0; dt < 8; dt++) {
      half8 vf;
#pragma unroll
      for (int j = 0; j < 8; j++)
        vf[j] = Vs[(quad * 8 + j) * 136 + dt * 16 + col];
      O[dt] = __builtin_amdgcn_mfma_f32_16x16x32_f16(pfrag, vf, O[dt], 0, 0, 0);
    }
  }

  float invl[4];
#pragma unroll
  for (int i = 0; i < 4; i++) invl[i] = 1.f / l_run[i];
#pragma unroll
  for (int i = 0; i < 4; i++) {
    int qr = qtile * 16 + quad * 4 + i;
    if (qr < 225) {
      h16* dst = AOh + ((size_t)win * 225 + qr) * CDIM + head * 128 + col;
#pragma unroll
      for (int dt = 0; dt < 8; dt++)
        dst[dt * 16] = (h16)(O[dt][i] * invl[i]);
    }
  }
}

extern "C" void kernel_launch(void* const* d_in, const int* in_sizes, int n_in,
                              void* d_out, int out_size, void* d_ws, size_t ws_size,
                              hipStream_t stream) {
  const float* x0    = (const float*)d_in[0];
  const float* x1    = (const float*)d_in[1];
  const float* Wqkv  = (const float*)d_in[2];
  const float* bqkv  = (const float*)d_in[3];
  const float* Wproj = (const float*)d_in[4];
  const float* bproj = (const float*)d_in[5];
  float* out = (float*)d_out;

  h16* Qh   = (h16*)d_ws;
  h16* Kh   = Qh + (size_t)NTOK * CDIM;
  h16* Vh   = Kh + (size_t)NTOK * CDIM;
  h16* X0AO = Vh + (size_t)NTOK * CDIM;         // aliased: X0h (pre-attn) / AOh (post-attn)
  h16* Kph  = X0AO + (size_t)NTOK * CDIM;
  h16* Vph  = Kph + (size_t)NPTOK * CDIM;
  h16* Wqkvt  = Vph + (size_t)NPTOK * CDIM;     // 1536 x 512
  h16* Wprojt = Wqkvt + (size_t)1536 * 512;     // 512 x 512

  // preconvert (x0 -> f16, weights -> transposed f16)
  cvt_x0<<<NTOK * CDIM / 1024, 256, 0, stream>>>(x0, X0AO);
  transpose_cvt<<<dim3(48, 16), 256, 0, stream>>>(Wqkv, Wqkvt, 512, 1536);
  transpose_cvt<<<dim3(16, 16), 256, 0, stream>>>(Wproj, Wprojt, 512, 512);

  gemm_qkv_mfma<<<dim3(254, 12), 256, 0, stream>>>(X0AO, Wqkvt, bqkv, Qh, Kh, Vh);
  gemm_pooled<<<dim3(12, 16), 256, 0, stream>>>(x1, Wqkv, bqkv, Kph, Vph);
  attn_kernel<<<dim3(144, 4, 4), 256, 0, stream>>>(Qh, Kh, Vh, Kph, Vph, X0AO);
  gemm_proj_mfma<<<dim3(254, 4), 256, 0, stream>>>(X0AO, Wprojt, bproj, out);
}

// Round 3
// 584.291 us; speedup vs baseline: 2.4616x; 1.1619x over previous
//
#include <hip/hip_runtime.h>

typedef _Float16 h16;
typedef __attribute__((ext_vector_type(8))) _Float16 half8;
typedef __attribute__((ext_vector_type(4))) _Float16 half4;
typedef __attribute__((ext_vector_type(2))) _Float16 half2v;
typedef __attribute__((ext_vector_type(4))) float float4v;

#define NTOK  32400   // 5*60*108
#define NPTOK 720     // 5*12*12
#define CDIM  512
#define SCALE 0.08838834764831845f

// valid-index table for the rolled halo (nonzero of stacked tl,tr,bl,br 5x9 masks)
__constant__ int VIR_TBL[120] = {
  5,6,7,8, 14,15,16,17, 23,24,25,26,
  27,28,29,30,31,32,33,34,35, 36,37,38,39,40,41,42,43,44,
  45,46,47,48, 54,55,56,57, 63,64,65,66,
  72,73,74,75,76,77,78,79,80, 81,82,83,84,85,86,87,88,89,
  90,91,92,93,94,95,96,97,98, 99,100,101,102,103,104,105,106,107,
  113,114,115,116, 122,123,124,125, 131,132,133,134,
  135,136,137,138,139,140,141,142,143, 144,145,146,147,148,149,150,151,152,
  153,154,155,156, 162,163,164,165, 171,172,173,174
};

// ---------------- token-index table: Tok[win][1056] ----------------------
// e >= 0, bit30 clear : window/halo token index into Kh/Vh
// e >= 0, bit30 set   : pooled token index into Kph/Vph
// e == -1             : masked pooled row (zero K/V, bias -100)
// e == -2             : pad row (bias -1e30)
__global__ __launch_bounds__(256) void build_tok(int* __restrict__ Tok) {
  const int win = blockIdx.x;
  const int wy = win / 12, wx = win % 12;
  for (int kidx = threadIdx.x; kidx < 1056; kidx += 256) {
    int e;
    if (kidx < 225) {
      int t = kidx / 45, pos = kidx % 45;
      int y = wy * 5 + pos / 9, x = wx * 9 + pos % 9;
      e = (t * 60 + y) * 108 + x;
    } else if (kidx < 825) {
      int jj = kidx - 225;
      int t = jj / 120, m = jj % 120;
      int vir = VIR_TBL[m];
      int p = vir / 45, pos = vir % 45;
      int r = pos / 9, c = pos % 9;
      int sy = (p < 2) ? -2 : 2;
      int sx = (p & 1) ? 4 : -4;
      int y = (wy * 5 + r - sy + 60) % 60;
      int x = (wx * 9 + c - sx + 108) % 108;
      e = (t * 60 + y) * 108 + x;
    } else if (kidx < 1050) {
      int jp = kidx - 825;
      int t = jp / 45, pos = jp % 45;
      int py = wy + pos / 9 - 2;
      int px = wx + pos % 9 - 4;
      e = (py >= 0 && py < 12 && px >= 0 && px < 12)
            ? ((t * 144 + py * 12 + px) | (1 << 30)) : -1;
    } else {
      e = -2;
    }
    Tok[win * 1056 + kidx] = e;
  }
}

// ---------------- cvt_x0: fp32 -> f16 elementwise ------------------------
__global__ __launch_bounds__(256) void cvt_x0(const float* __restrict__ src,
                                              h16* __restrict__ dst) {
  int idx = blockIdx.x * 256 + threadIdx.x;
  float4 v = *(const float4*)(src + (size_t)idx * 4);
  half4 h;
  h[0] = (h16)v.x; h[1] = (h16)v.y; h[2] = (h16)v.z; h[3] = (h16)v.w;
  *(half4*)(dst + (size_t)idx * 4) = h;
}

// ------------- transpose_cvt: src R x C fp32 -> dst C x R f16 ------------
__global__ __launch_bounds__(256) void transpose_cvt(const float* __restrict__ src,
                                                     h16* __restrict__ dst,
                                                     int R, int C) {
  __shared__ float T[32][33];
  const int t = threadIdx.x;
  const int ct = blockIdx.x * 32;
  const int rt = blockIdx.y * 32;
  const int c = t & 31, r0 = (t >> 5) * 4;
#pragma unroll
  for (int i = 0; i < 4; i++)
    T[r0 + i][c] = src[(size_t)(rt + r0 + i) * C + ct + c];
  __syncthreads();
#pragma unroll
  for (int i = 0; i < 4; i++)
    dst[(size_t)(ct + r0 + i) * R + rt + c] = (h16)T[c][r0 + i];
}

// ---------------- MFMA GEMM core LDS shapes ------------------------------
struct StageLDS { h16 Ah[128][40]; h16 Bh[128][40]; };
union GemmLDS { StageLDS s; h16 Cs[128][136]; };

// GEMM 1: X0h @ Wqkvt^T + b -> Q,K,V (f16). Bt layout [n][k].
__global__ __launch_bounds__(256) void gemm_qkv_mfma(
    const h16* __restrict__ A, const h16* __restrict__ Bt,
    const float* __restrict__ bias,
    h16* __restrict__ Q, h16* __restrict__ K, h16* __restrict__ V)
{
  __shared__ GemmLDS u;
  const int tid = threadIdx.x;
  const int lane = tid & 63, wv = tid >> 6;
  const int col = lane & 15, quad = lane >> 4;
  const int bm = blockIdx.x, bn = blockIdx.y;
  const int mo = (wv & 1) * 64, no = (wv >> 1) * 64;

  float4v acc[4][4];
#pragma unroll
  for (int i = 0; i < 4; i++)
#pragma unroll
    for (int j = 0; j < 4; j++) acc[i][j] = (float4v){0.f, 0.f, 0.f, 0.f};

  const int srow = tid >> 1, skoff = (tid & 1) * 16;
  const int arow = bm * 128 + srow;
  const h16* Ap = A + (size_t)arow * 512 + skoff;
  const h16* Bp = Bt + (size_t)(bn * 128 + srow) * 512 + skoff;

  for (int k0 = 0; k0 < 512; k0 += 32) {
    half8 a0, a1, b0, b1;
    if (arow < NTOK) {
      a0 = *(const half8*)(Ap + k0);
      a1 = *(const half8*)(Ap + k0 + 8);
    } else {
#pragma unroll
      for (int jj = 0; jj < 8; jj++) { a0[jj] = (h16)0.f; a1[jj] = (h16)0.f; }
    }
    b0 = *(const half8*)(Bp + k0);
    b1 = *(const half8*)(Bp + k0 + 8);
    __syncthreads();
    *(half8*)&u.s.Ah[srow][skoff] = a0;
    *(half8*)&u.s.Ah[srow][skoff + 8] = a1;
    *(half8*)&u.s.Bh[srow][skoff] = b0;
    *(half8*)&u.s.Bh[srow][skoff + 8] = b1;
    __syncthreads();

    half8 afr[4], bfr[4];
#pragma unroll
    for (int i = 0; i < 4; i++)
      afr[i] = *(const half8*)&u.s.Ah[mo + i * 16 + col][quad * 8];
#pragma unroll
    for (int j = 0; j < 4; j++)
      bfr[j] = *(const half8*)&u.s.Bh[no + j * 16 + col][quad * 8];
#pragma unroll
    for (int i = 0; i < 4; i++)
#pragma unroll
      for (int j = 0; j < 4; j++)
        acc[i][j] = __builtin_amdgcn_mfma_f32_16x16x32_f16(afr[i], bfr[j], acc[i][j], 0, 0, 0);
  }

  __syncthreads();
  float bv[4];
#pragma unroll
  for (int j = 0; j < 4; j++) bv[j] = bias[bn * 128 + no + j * 16 + col];
#pragma unroll
  for (int i = 0; i < 4; i++)
#pragma unroll
    for (int j = 0; j < 4; j++)
#pragma unroll
      for (int r = 0; r < 4; r++)
        u.Cs[mo + i * 16 + quad * 4 + r][no + j * 16 + col] = (h16)(acc[i][j][r] + bv[j]);
  __syncthreads();

  const int row_l = tid >> 1, halfseg = (tid & 1) * 64;
  const int row_g = bm * 128 + row_l;
  const int jsel = bn >> 2;
  const int ch0 = (bn & 3) * 128 + halfseg;
  h16* dst = (jsel == 0) ? Q : (jsel == 1) ? K : V;
  if (row_g < NTOK) {
#pragma unroll
    for (int c = 0; c < 64; c += 8)
      *(half8*)&dst[(size_t)row_g * 512 + ch0 + c] = *(const half8*)&u.Cs[row_l][halfseg + c];
  }
}

// GEMM 3: AO(f16) @ Wprojt^T + b -> out (fp32)
__global__ __launch_bounds__(256) void gemm_proj_mfma(
    const h16* __restrict__ A, const h16* __restrict__ Bt,
    const float* __restrict__ bias, float* __restrict__ out)
{
  __shared__ StageLDS s;
  const int tid = threadIdx.x;
  const int lane = tid & 63, wv = tid >> 6;
  const int col = lane & 15, quad = lane >> 4;
  const int bm = blockIdx.x, bn = blockIdx.y;
  const int mo = (wv & 1) * 64, no = (wv >> 1) * 64;

  float4v acc[4][4];
#pragma unroll
  for (int i = 0; i < 4; i++)
#pragma unroll
    for (int j = 0; j < 4; j++) acc[i][j] = (float4v){0.f, 0.f, 0.f, 0.f};

  const int srow = tid >> 1, skoff = (tid & 1) * 16;
  const int arow = bm * 128 + srow;
  const h16* Ap = A + (size_t)arow * 512 + skoff;
  const h16* Bp = Bt + (size_t)(bn * 128 + srow) * 512 + skoff;

  for (int k0 = 0; k0 < 512; k0 += 32) {
    half8 a0, a1, b0, b1;
    if (arow < NTOK) {
      a0 = *(const half8*)(Ap + k0);
      a1 = *(const half8*)(Ap + k0 + 8);
    } else {
#pragma unroll
      for (int jj = 0; jj < 8; jj++) { a0[jj] = (h16)0.f; a1[jj] = (h16)0.f; }
    }
    b0 = *(const half8*)(Bp + k0);
    b1 = *(const half8*)(Bp + k0 + 8);
    __syncthreads();
    *(half8*)&s.Ah[srow][skoff] = a0;
    *(half8*)&s.Ah[srow][skoff + 8] = a1;
    *(half8*)&s.Bh[srow][skoff] = b0;
    *(half8*)&s.Bh[srow][skoff + 8] = b1;
    __syncthreads();

    half8 afr[4], bfr[4];
#pragma unroll
    for (int i = 0; i < 4; i++)
      afr[i] = *(const half8*)&s.Ah[mo + i * 16 + col][quad * 8];
#pragma unroll
    for (int j = 0; j < 4; j++)
      bfr[j] = *(const half8*)&s.Bh[no + j * 16 + col][quad * 8];
#pragma unroll
    for (int i = 0; i < 4; i++)
#pragma unroll
      for (int j = 0; j < 4; j++)
        acc[i][j] = __builtin_amdgcn_mfma_f32_16x16x32_f16(afr[i], bfr[j], acc[i][j], 0, 0, 0);
  }

  float bv[4];
#pragma unroll
  for (int j = 0; j < 4; j++) bv[j] = bias[bn * 128 + no + j * 16 + col];
#pragma unroll
  for (int i = 0; i < 4; i++) {
#pragma unroll
    for (int r = 0; r < 4; r++) {
      int row_g = bm * 128 + mo + i * 16 + quad * 4 + r;
      if (row_g < NTOK) {
#pragma unroll
        for (int j = 0; j < 4; j++)
          out[(size_t)row_g * 512 + bn * 128 + no + j * 16 + col] = acc[i][j][r] + bv[j];
      }
    }
  }
}

// ---------------- GEMM 2: pooled x1 @ W_qkv[:,512:] -> Kp,Vp -------------
__global__ __launch_bounds__(256) void gemm_pooled(
    const float* __restrict__ A, const float* __restrict__ B,
    const float* __restrict__ bias,
    h16* __restrict__ Kp, h16* __restrict__ Vp)
{
  __shared__ float As[64][17];
  __shared__ float Bs[16][64];
  const int tid = threadIdx.x;
  const int bm = blockIdx.x, bn = blockIdx.y;
  const int tm = tid >> 4, tn = tid & 15;
  const int lrow = tid >> 2, lk = (tid & 3) * 4;
  const int brow = tid >> 4, bcol = (tid & 15) * 4;
  float acc[4][4] = {};
  const int orow = bm * 64 + lrow;
  int srow = 0;
  if (orow < NPTOK) { int t = orow / 144, rem = orow % 144; srow = rem * 5 + t; }
  const float* Ap = A + (size_t)srow * 512 + lk;
  const float* Bp = B + (size_t)brow * 1536 + 512 + bn * 64 + bcol;

  for (int k0 = 0; k0 < 512; k0 += 16) {
    float4 av = make_float4(0.f, 0.f, 0.f, 0.f);
    if (orow < NPTOK) av = *(const float4*)(Ap + k0);
    float4 bv = *(const float4*)(Bp + (size_t)k0 * 1536);
    As[lrow][lk + 0] = av.x; As[lrow][lk + 1] = av.y;
    As[lrow][lk + 2] = av.z; As[lrow][lk + 3] = av.w;
    *(float4*)&Bs[brow][bcol] = bv;
    __syncthreads();
#pragma unroll
    for (int kk = 0; kk < 16; kk++) {
      float a[4];
#pragma unroll
      for (int i = 0; i < 4; i++) a[i] = As[tm * 4 + i][kk];
      float4 b = *(const float4*)&Bs[kk][tn * 4];
#pragma unroll
      for (int i = 0; i < 4; i++) {
        acc[i][0] = fmaf(a[i], b.x, acc[i][0]);
        acc[i][1] = fmaf(a[i], b.y, acc[i][1]);
        acc[i][2] = fmaf(a[i], b.z, acc[i][2]);
        acc[i][3] = fmaf(a[i], b.w, acc[i][3]);
      }
    }
    __syncthreads();
  }
  const int nl = bn * 64 + tn * 4;
  const int j = nl >> 9;
  const int ch = nl & 511;
  h16* dst = (j == 0) ? Kp : Vp;
#pragma unroll
  for (int i = 0; i < 4; i++) {
    int r = bm * 64 + tm * 4 + i;
    if (r < NPTOK) {
#pragma unroll
      for (int c = 0; c < 4; c++)
        dst[(size_t)r * 512 + ch + c] = (h16)(acc[i][c] + bias[512 + nl + c]);
    }
  }
}

// ---------------- Attention v2 ------------------------------------------
// grid (144 win, 4 head, 2 qgroup), block 256 = 4 waves.
// Wave wv owns q-tiles {qg*8 + wv*2, +1} (16 rows each). K/V fragments are
// read once per wave-step and shared across both tiles.
// Vt: transposed V in LDS, row-stride 36 halfs (dword stride 18, odd ->
// ~2-way conflicts on b64 reads), rowpair rotation rp'=(rp+4*(cg&3))&15.
__global__ __launch_bounds__(256, 3) void attn_kernel(
    const h16* __restrict__ Qh, const h16* __restrict__ Kh,
    const h16* __restrict__ Vh, const h16* __restrict__ Kph,
    const h16* __restrict__ Vph, const int* __restrict__ Tok,
    h16* __restrict__ AOh)
{
  __shared__ h16 Ks[32 * 136];
  __shared__ h16 Vt[128 * 36];
  __shared__ h16 Ps[4][16 * 36];
  __shared__ float biasLDS[32];

  const int tid = threadIdx.x;
  const int lane = tid & 63;
  const int wv = tid >> 6;
  const int win = blockIdx.x;
  const int head = blockIdx.y;
  const int qg = blockIdx.z;
  const int wy = win / 12, wx = win % 12;
  const int col = lane & 15;
  const int quad = lane >> 4;
  const int* TokW = Tok + win * 1056;

  // ---- Q fragments for 2 tiles (A-layout: m=col, k=quad*8+j) ----
  half8 qfrag[2][4];
  int tile0 = qg * 8 + wv * 2;
#pragma unroll
  for (int tt = 0; tt < 2; tt++) {
    int qrow = (tile0 + tt) * 16 + col;
    if (qrow < 225) {
      int t = qrow / 45, pos = qrow % 45;
      int y = wy * 5 + pos / 9, x = wx * 9 + pos % 9;
      const h16* qsrc = Qh + (size_t)((t * 60 + y) * 108 + x) * CDIM + head * 128;
#pragma unroll
      for (int dc = 0; dc < 4; dc++)
        qfrag[tt][dc] = *(const half8*)(qsrc + dc * 32 + quad * 8);
    } else {
#pragma unroll
      for (int dc = 0; dc < 4; dc++)
#pragma unroll
        for (int jj = 0; jj < 8; jj++) qfrag[tt][dc][jj] = (h16)0.f;
    }
  }

  float4v O[2][8];
#pragma unroll
  for (int tt = 0; tt < 2; tt++)
#pragma unroll
    for (int i = 0; i < 8; i++) O[tt][i] = (float4v){0.f, 0.f, 0.f, 0.f};
  float m_run[2][4], l_run[2][4];
#pragma unroll
  for (int tt = 0; tt < 2; tt++)
#pragma unroll
    for (int i = 0; i < 4; i++) { m_run[tt][i] = -INFINITY; l_run[tt][i] = 0.f; }

  // staging roles
  const int krow = tid >> 3, kseg = tid & 7;      // K: 32 rows x 8 segs of 16
  const int vrp = tid >> 4, vcg = tid & 15;       // V: 16 rowpairs x 16 ch-groups of 8
  const int kch = head * 128 + kseg * 16;
  const int vch = head * 128 + vcg * 8;
  const int vrot = (vcg & 3) * 4;                 // rowpair rotation for this cg

  for (int step = 0; step < 33; ++step) {
    // ---- issue gathers (global) ----
    int eK = TokW[step * 32 + krow];
    int eVa = TokW[step * 32 + 2 * vrp];
    int eVb = TokW[step * 32 + 2 * vrp + 1];
    half8 k0, k1, va, vb;
#pragma unroll
    for (int jj = 0; jj < 8; jj++) { k0[jj] = (h16)0.f; k1[jj] = (h16)0.f; va[jj] = (h16)0.f; vb[jj] = (h16)0.f; }
    if (eK >= 0) {
      const h16* s = ((eK & (1 << 30)) ? Kph + (size_t)(eK & 0x3FFFFFFF) * CDIM
                                       : Kh + (size_t)eK * CDIM) + kch;
      k0 = *(const half8*)s;
      k1 = *(const half8*)(s + 8);
    }
    if (eVa >= 0) {
      const h16* s = ((eVa & (1 << 30)) ? Vph + (size_t)(eVa & 0x3FFFFFFF) * CDIM
                                        : Vh + (size_t)eVa * CDIM) + vch;
      va = *(const half8*)s;
    }
    if (eVb >= 0) {
      const h16* s = ((eVb & (1 << 30)) ? Vph + (size_t)(eVb & 0x3FFFFFFF) * CDIM
                                        : Vh + (size_t)eVb * CDIM) + vch;
      vb = *(const half8*)s;
    }
    __syncthreads();   // previous iteration's LDS reads complete
    // K rows
    *(half8*)&Ks[krow * 136 + kseg * 16] = k0;
    *(half8*)&Ks[krow * 136 + kseg * 16 + 8] = k1;
    // V transposed (rowpair-rotated)
    {
      int rp = (vrp + vrot) & 15;
#pragma unroll
      for (int i = 0; i < 8; i++) {
        half2v w; w[0] = va[i]; w[1] = vb[i];
        *(half2v*)&Vt[(vcg * 8 + i) * 36 + rp * 2] = w;
      }
    }
    if (kseg == 0)
      biasLDS[krow] = (eK == -1) ? -100.f : ((eK == -2) ? -1e30f : 0.f);
    __syncthreads();

    // ---- S = Q K^T : shared K fragments, 2 tiles ----
    float4v s0[2] = {{0.f,0.f,0.f,0.f},{0.f,0.f,0.f,0.f}};
    float4v s1[2] = {{0.f,0.f,0.f,0.f},{0.f,0.f,0.f,0.f}};
#pragma unroll
    for (int dc = 0; dc < 4; dc++) {
      half8 b0 = *(const half8*)&Ks[col * 136 + dc * 32 + quad * 8];
      half8 b1 = *(const half8*)&Ks[(col + 16) * 136 + dc * 32 + quad * 8];
#pragma unroll
      for (int tt = 0; tt < 2; tt++) {
        s0[tt] = __builtin_amdgcn_mfma_f32_16x16x32_f16(qfrag[tt][dc], b0, s0[tt], 0, 0, 0);
        s1[tt] = __builtin_amdgcn_mfma_f32_16x16x32_f16(qfrag[tt][dc], b1, s1[tt], 0, 0, 0);
      }
    }

    float b0s = biasLDS[col], b1s = biasLDS[col + 16];

    // ---- online softmax + P write (both tiles) ----
    half8 pfrag[2];
#pragma unroll
    for (int tt = 0; tt < 2; tt++) {
      float alpha[4], p0[4], p1[4];
#pragma unroll
      for (int i = 0; i < 4; i++) {
        float sa = s0[tt][i] * SCALE + b0s;
        float sb = s1[tt][i] * SCALE + b1s;
        float mx = fmaxf(sa, sb);
        mx = fmaxf(mx, __shfl_xor(mx, 1));
        mx = fmaxf(mx, __shfl_xor(mx, 2));
        mx = fmaxf(mx, __shfl_xor(mx, 4));
        mx = fmaxf(mx, __shfl_xor(mx, 8));
        float mn = fmaxf(m_run[tt][i], mx);
        alpha[i] = __expf(m_run[tt][i] - mn);
        p0[i] = __expf(sa - mn);
        p1[i] = __expf(sb - mn);
        float rs = p0[i] + p1[i];
        rs += __shfl_xor(rs, 1);
        rs += __shfl_xor(rs, 2);
        rs += __shfl_xor(rs, 4);
        rs += __shfl_xor(rs, 8);
        l_run[tt][i] = l_run[tt][i] * alpha[i] + rs;
        m_run[tt][i] = mn;
      }
#pragma unroll
      for (int dt = 0; dt < 8; dt++)
#pragma unroll
        for (int i = 0; i < 4; i++) O[tt][dt][i] *= alpha[i];

      h16* Pw = &Ps[wv][0];
#pragma unroll
      for (int i = 0; i < 4; i++) {
        int qr = quad * 4 + i;
        Pw[qr * 36 + col] = (h16)p0[i];
        Pw[qr * 36 + col + 16] = (h16)p1[i];
      }
      // A-layout read back (within-wave, compiler inserts lgkmcnt wait)
      half4 plo = *(const half4*)&Pw[col * 36 + quad * 8];
      half4 phi = *(const half4*)&Pw[col * 36 + quad * 8 + 4];
#pragma unroll
      for (int jj = 0; jj < 4; jj++) { pfrag[tt][jj] = plo[jj]; pfrag[tt][jj + 4] = phi[jj]; }
    }

    // ---- O += P V : shared V fragments, 2 tiles ----
#pragma unroll
    for (int dt = 0; dt < 8; dt++) {
      int ch = dt * 16 + col;
      int g4 = ((dt * 2 + (col >> 3)) & 3) * 4;
      int x0 = (quad * 4 + g4) & 15;
      int x1 = (quad * 4 + 2 + g4) & 15;
      half4 lo = *(const half4*)&Vt[ch * 36 + x0 * 2];
      half4 hi = *(const half4*)&Vt[ch * 36 + x1 * 2];
      half8 vf;
#pragma unroll
      for (int jj = 0; jj < 4; jj++) { vf[jj] = lo[jj]; vf[jj + 4] = hi[jj]; }
#pragma unroll
      for (int tt = 0; tt < 2; tt++)
        O[tt][dt] = __builtin_amdgcn_mfma_f32_16x16x32_f16(pfrag[tt], vf, O[tt][dt], 0, 0, 0);
    }
  }

  // ---- epilogue ----
#pragma unroll
  for (int tt = 0; tt < 2; tt++) {
#pragma unroll
    for (int i = 0; i < 4; i++) {
      int qr = (tile0 + tt) * 16 + quad * 4 + i;
      if (qr < 225) {
        float invl = 1.f / l_run[tt][i];
        h16* dst = AOh + ((size_t)win * 225 + qr) * CDIM + head * 128 + col;
#pragma unroll
        for (int dt = 0; dt < 8; dt++)
          dst[dt * 16] = (h16)(O[tt][dt][i] * invl);
      }
    }
  }
}

extern "C" void kernel_launch(void* const* d_in, const int* in_sizes, int n_in,
                              void* d_out, int out_size, void* d_ws, size_t ws_size,
                              hipStream_t stream) {
  const float* x0    = (const float*)d_in[0];
  const float* x1    = (const float*)d_in[1];
  const float* Wqkv  = (const float*)d_in[2];
  const float* bqkv  = (const float*)d_in[3];
  const float* Wproj = (const float*)d_in[4];
  const float* bproj = (const float*)d_in[5];
  float* out = (float*)d_out;

  h16* Qh   = (h16*)d_ws;
  h16* Kh   = Qh + (size_t)NTOK * CDIM;
  h16* Vh   = Kh + (size_t)NTOK * CDIM;
  h16* X0AO = Vh + (size_t)NTOK * CDIM;      // aliased: X0h (pre-attn) / AOh (post-attn)
  h16* Kph  = X0AO + (size_t)NTOK * CDIM;
  h16* Vph  = Kph + (size_t)NPTOK * CDIM;
  h16* Wqkvt  = Vph + (size_t)NPTOK * CDIM;  // 1536 x 512
  h16* Wprojt = Wqkvt + (size_t)1536 * 512;  // 512 x 512
  int* Tok = (int*)(Wprojt + (size_t)512 * 512);  // 144 x 1056

  build_tok<<<144, 256, 0, stream>>>(Tok);
  cvt_x0<<<NTOK * CDIM / 1024, 256, 0, stream>>>(x0, X0AO);
  transpose_cvt<<<dim3(48, 16), 256, 0, stream>>>(Wqkv, Wqkvt, 512, 1536);
  transpose_cvt<<<dim3(16, 16), 256, 0, stream>>>(Wproj, Wprojt, 512, 512);

  gemm_qkv_mfma<<<dim3(254, 12), 256, 0, stream>>>(X0AO, Wqkvt, bqkv, Qh, Kh, Vh);
  gemm_pooled<<<dim3(12, 16), 256, 0, stream>>>(x1, Wqkv, bqkv, Kph, Vph);
  attn_kernel<<<dim3(144, 4, 2), 256, 0, stream>>>(Qh, Kh, Vh, Kph, Vph, Tok, X0AO);
  gemm_proj_mfma<<<dim3(254, 4), 256, 0, stream>>>(X0AO, Wprojt, bproj, out);
}

// Round 4
// 514.280 us; speedup vs baseline: 2.7967x; 1.1361x over previous
//
#include <hip/hip_runtime.h>

typedef _Float16 h16;
typedef __attribute__((ext_vector_type(8))) _Float16 half8;
typedef __attribute__((ext_vector_type(4))) _Float16 half4;
typedef __attribute__((ext_vector_type(2))) _Float16 half2v;
typedef __attribute__((ext_vector_type(4))) float float4v;

#define NTOK  32400   // 5*60*108
#define NPTOK 720     // 5*12*12
#define CDIM  512
#define SCALE 0.08838834764831845f
#define ZROW  NTOK            // zero row index in unified K/V buffers
#define PROW  (NTOK + 1)      // pooled rows start

// valid-index table for the rolled halo (nonzero of stacked tl,tr,bl,br 5x9 masks)
__constant__ int VIR_TBL[120] = {
  5,6,7,8, 14,15,16,17, 23,24,25,26,
  27,28,29,30,31,32,33,34,35, 36,37,38,39,40,41,42,43,44,
  45,46,47,48, 54,55,56,57, 63,64,65,66,
  72,73,74,75,76,77,78,79,80, 81,82,83,84,85,86,87,88,89,
  90,91,92,93,94,95,96,97,98, 99,100,101,102,103,104,105,106,107,
  113,114,115,116, 122,123,124,125, 131,132,133,134,
  135,136,137,138,139,140,141,142,143, 144,145,146,147,148,149,150,151,152,
  153,154,155,156, 162,163,164,165, 171,172,173,174
};

// ---------------- token row table + per-step valid mask -------------------
// Tok[win][kidx] = row into unified K/V buffers (ZROW for masked/pad).
// WMask[win][step] bit r = row (step*32+r) contributes to the softmax sum.
__global__ __launch_bounds__(256) void build_tok(int* __restrict__ Tok,
                                                 int* __restrict__ WMask) {
  const int win = blockIdx.x;
  const int wy = win / 12, wx = win % 12;
  for (int kidx = threadIdx.x; kidx < 1056; kidx += 256) {
    int e;
    if (kidx < 225) {
      int t = kidx / 45, pos = kidx % 45;
      int y = wy * 5 + pos / 9, x = wx * 9 + pos % 9;
      e = (t * 60 + y) * 108 + x;
    } else if (kidx < 825) {
      int jj = kidx - 225;
      int t = jj / 120, m = jj % 120;
      int vir = VIR_TBL[m];
      int p = vir / 45, pos = vir % 45;
      int r = pos / 9, c = pos % 9;
      int sy = (p < 2) ? -2 : 2;
      int sx = (p & 1) ? 4 : -4;
      int y = (wy * 5 + r - sy + 60) % 60;
      int x = (wx * 9 + c - sx + 108) % 108;
      e = (t * 60 + y) * 108 + x;
    } else if (kidx < 1050) {
      int jp = kidx - 825;
      int t = jp / 45, pos = jp % 45;
      int py = wy + pos / 9 - 2;
      int px = wx + pos % 9 - 4;
      e = (py >= 0 && py < 12 && px >= 0 && px < 12)
            ? (PROW + t * 144 + py * 12 + px) : ZROW;
    } else {
      e = ZROW;
    }
    Tok[win * 1056 + kidx] = e;
  }
  if (threadIdx.x < 33) {
    int m = 0;
#pragma unroll 1
    for (int r = 0; r < 32; r++) {
      int kidx = threadIdx.x * 32 + r;
      bool v;
      if (kidx < 825) v = true;
      else if (kidx < 1050) {
        int jp = kidx - 825, pos = jp % 45;
        int py = wy + pos / 9 - 2, px = wx + pos % 9 - 4;
        v = (py >= 0 && py < 12 && px >= 0 && px < 12);
      } else v = false;
      m |= (v ? 1 : 0) << r;
    }
    WMask[win * 33 + threadIdx.x] = m;
  }
}

// ---------------- zero_rows: clear the unified-buffer zero rows ----------
__global__ __launch_bounds__(256) void zero_rows(h16* __restrict__ a,
                                                 h16* __restrict__ b) {
  for (int k = threadIdx.x; k < 512; k += 256) {
    a[(size_t)ZROW * CDIM + k] = (h16)0.f;
    b[(size_t)ZROW * CDIM + k] = (h16)0.f;
  }
}

// ------------- transpose_cvt: src R x C fp32 -> dst C x R f16 ------------
__global__ __launch_bounds__(256) void transpose_cvt(const float* __restrict__ src,
                                                     h16* __restrict__ dst,
                                                     int R, int C) {
  __shared__ float T[32][33];
  const int t = threadIdx.x;
  const int ct = blockIdx.x * 32;
  const int rt = blockIdx.y * 32;
  const int c = t & 31, r0 = (t >> 5) * 4;
#pragma unroll
  for (int i = 0; i < 4; i++)
    T[r0 + i][c] = src[(size_t)(rt + r0 + i) * C + ct + c];
  __syncthreads();
#pragma unroll
  for (int i = 0; i < 4; i++)
    dst[(size_t)(ct + r0 + i) * R + rt + c] = (h16)T[c][r0 + i];
}

// ---------------- MFMA GEMM core LDS shapes ------------------------------
struct StageLDS { h16 Ah[128][40]; h16 Bh[128][40]; };
union GemmLDS { StageLDS s; h16 Cs[128][136]; };

// GEMM 1: x0(fp32, cvt fused) @ Wqkvt^T + b -> Q,K,V (f16). Bt layout [n][k].
__global__ __launch_bounds__(256) void gemm_qkv_mfma(
    const float* __restrict__ A, const h16* __restrict__ Bt,
    const float* __restrict__ bias,
    h16* __restrict__ Q, h16* __restrict__ K, h16* __restrict__ V)
{
  __shared__ GemmLDS u;
  const int tid = threadIdx.x;
  const int lane = tid & 63, wv = tid >> 6;
  const int col = lane & 15, quad = lane >> 4;
  const int bm = blockIdx.x, bn = blockIdx.y;
  const int mo = (wv & 1) * 64, no = (wv >> 1) * 64;

  float4v acc[4][4];
#pragma unroll
  for (int i = 0; i < 4; i++)
#pragma unroll
    for (int j = 0; j < 4; j++) acc[i][j] = (float4v){0.f, 0.f, 0.f, 0.f};

  const int srow = tid >> 1, skoff = (tid & 1) * 16;
  const int arow = bm * 128 + srow;
  const float* Ap = A + (size_t)arow * 512 + skoff;
  const h16* Bp = Bt + (size_t)(bn * 128 + srow) * 512 + skoff;

  for (int k0 = 0; k0 < 512; k0 += 32) {
    half8 a0, a1, b0, b1;
    if (arow < NTOK) {
      float4 f0 = *(const float4*)(Ap + k0);
      float4 f1 = *(const float4*)(Ap + k0 + 4);
      float4 f2 = *(const float4*)(Ap + k0 + 8);
      float4 f3 = *(const float4*)(Ap + k0 + 12);
      a0[0]=(h16)f0.x; a0[1]=(h16)f0.y; a0[2]=(h16)f0.z; a0[3]=(h16)f0.w;
      a0[4]=(h16)f1.x; a0[5]=(h16)f1.y; a0[6]=(h16)f1.z; a0[7]=(h16)f1.w;
      a1[0]=(h16)f2.x; a1[1]=(h16)f2.y; a1[2]=(h16)f2.z; a1[3]=(h16)f2.w;
      a1[4]=(h16)f3.x; a1[5]=(h16)f3.y; a1[6]=(h16)f3.z; a1[7]=(h16)f3.w;
    } else {
#pragma unroll
      for (int jj = 0; jj < 8; jj++) { a0[jj] = (h16)0.f; a1[jj] = (h16)0.f; }
    }
    b0 = *(const half8*)(Bp + k0);
    b1 = *(const half8*)(Bp + k0 + 8);
    __syncthreads();
    *(half8*)&u.s.Ah[srow][skoff] = a0;
    *(half8*)&u.s.Ah[srow][skoff + 8] = a1;
    *(half8*)&u.s.Bh[srow][skoff] = b0;
    *(half8*)&u.s.Bh[srow][skoff + 8] = b1;
    __syncthreads();

    half8 afr[4], bfr[4];
#pragma unroll
    for (int i = 0; i < 4; i++)
      afr[i] = *(const half8*)&u.s.Ah[mo + i * 16 + col][quad * 8];
#pragma unroll
    for (int j = 0; j < 4; j++)
      bfr[j] = *(const half8*)&u.s.Bh[no + j * 16 + col][quad * 8];
#pragma unroll
    for (int i = 0; i < 4; i++)
#pragma unroll
      for (int j = 0; j < 4; j++)
        acc[i][j] = __builtin_amdgcn_mfma_f32_16x16x32_f16(afr[i], bfr[j], acc[i][j], 0, 0, 0);
  }

  __syncthreads();
  float bv[4];
#pragma unroll
  for (int j = 0; j < 4; j++) bv[j] = bias[bn * 128 + no + j * 16 + col];
#pragma unroll
  for (int i = 0; i < 4; i++)
#pragma unroll
    for (int j = 0; j < 4; j++)
#pragma unroll
      for (int r = 0; r < 4; r++)
        u.Cs[mo + i * 16 + quad * 4 + r][no + j * 16 + col] = (h16)(acc[i][j][r] + bv[j]);
  __syncthreads();

  const int row_l = tid >> 1, halfseg = (tid & 1) * 64;
  const int row_g = bm * 128 + row_l;
  const int jsel = bn >> 2;
  const int ch0 = (bn & 3) * 128 + halfseg;
  h16* dst = (jsel == 0) ? Q : (jsel == 1) ? K : V;
  if (row_g < NTOK) {
#pragma unroll
    for (int c = 0; c < 64; c += 8)
      *(half8*)&dst[(size_t)row_g * 512 + ch0 + c] = *(const half8*)&u.Cs[row_l][halfseg + c];
  }
}

// GEMM 3: AO(f16) @ Wprojt^T + b -> out (fp32)
__global__ __launch_bounds__(256) void gemm_proj_mfma(
    const h16* __restrict__ A, const h16* __restrict__ Bt,
    const float* __restrict__ bias, float* __restrict__ out)
{
  __shared__ StageLDS s;
  const int tid = threadIdx.x;
  const int lane = tid & 63, wv = tid >> 6;
  const int col = lane & 15, quad = lane >> 4;
  const int bm = blockIdx.x, bn = blockIdx.y;
  const int mo = (wv & 1) * 64, no = (wv >> 1) * 64;

  float4v acc[4][4];
#pragma unroll
  for (int i = 0; i < 4; i++)
#pragma unroll
    for (int j = 0; j < 4; j++) acc[i][j] = (float4v){0.f, 0.f, 0.f, 0.f};

  const int srow = tid >> 1, skoff = (tid & 1) * 16;
  const int arow = bm * 128 + srow;
  const h16* Ap = A + (size_t)arow * 512 + skoff;
  const h16* Bp = Bt + (size_t)(bn * 128 + srow) * 512 + skoff;

  for (int k0 = 0; k0 < 512; k0 += 32) {
    half8 a0, a1, b0, b1;
    if (arow < NTOK) {
      a0 = *(const half8*)(Ap + k0);
      a1 = *(const half8*)(Ap + k0 + 8);
    } else {
#pragma unroll
      for (int jj = 0; jj < 8; jj++) { a0[jj] = (h16)0.f; a1[jj] = (h16)0.f; }
    }
    b0 = *(const half8*)(Bp + k0);
    b1 = *(const half8*)(Bp + k0 + 8);
    __syncthreads();
    *(half8*)&s.Ah[srow][skoff] = a0;
    *(half8*)&s.Ah[srow][skoff + 8] = a1;
    *(half8*)&s.Bh[srow][skoff] = b0;
    *(half8*)&s.Bh[srow][skoff + 8] = b1;
    __syncthreads();

    half8 afr[4], bfr[4];
#pragma unroll
    for (int i = 0; i < 4; i++)
      afr[i] = *(const half8*)&s.Ah[mo + i * 16 + col][quad * 8];
#pragma unroll
    for (int j = 0; j < 4; j++)
      bfr[j] = *(const half8*)&s.Bh[no + j * 16 + col][quad * 8];
#pragma unroll
    for (int i = 0; i < 4; i++)
#pragma unroll
      for (int j = 0; j < 4; j++)
        acc[i][j] = __builtin_amdgcn_mfma_f32_16x16x32_f16(afr[i], bfr[j], acc[i][j], 0, 0, 0);
  }

  float bv[4];
#pragma unroll
  for (int j = 0; j < 4; j++) bv[j] = bias[bn * 128 + no + j * 16 + col];
#pragma unroll
  for (int i = 0; i < 4; i++) {
#pragma unroll
    for (int r = 0; r < 4; r++) {
      int row_g = bm * 128 + mo + i * 16 + quad * 4 + r;
      if (row_g < NTOK) {
#pragma unroll
        for (int j = 0; j < 4; j++)
          out[(size_t)row_g * 512 + bn * 128 + no + j * 16 + col] = acc[i][j][r] + bv[j];
      }
    }
  }
}

// ---------------- GEMM 2: pooled x1 @ W_qkv[:,512:] -> Kp,Vp -------------
__global__ __launch_bounds__(256) void gemm_pooled(
    const float* __restrict__ A, const float* __restrict__ B,
    const float* __restrict__ bias,
    h16* __restrict__ Kp, h16* __restrict__ Vp)
{
  __shared__ float As[64][17];
  __shared__ float Bs[16][64];
  const int tid = threadIdx.x;
  const int bm = blockIdx.x, bn = blockIdx.y;
  const int tm = tid >> 4, tn = tid & 15;
  const int lrow = tid >> 2, lk = (tid & 3) * 4;
  const int brow = tid >> 4, bcol = (tid & 15) * 4;
  float acc[4][4] = {};
  const int orow = bm * 64 + lrow;
  int srow = 0;
  if (orow < NPTOK) { int t = orow / 144, rem = orow % 144; srow = rem * 5 + t; }
  const float* Ap = A + (size_t)srow * 512 + lk;
  const float* Bp = B + (size_t)brow * 1536 + 512 + bn * 64 + bcol;

  for (int k0 = 0; k0 < 512; k0 += 16) {
    float4 av = make_float4(0.f, 0.f, 0.f, 0.f);
    if (orow < NPTOK) av = *(const float4*)(Ap + k0);
    float4 bv = *(const float4*)(Bp + (size_t)k0 * 1536);
    As[lrow][lk + 0] = av.x; As[lrow][lk + 1] = av.y;
    As[lrow][lk + 2] = av.z; As[lrow][lk + 3] = av.w;
    *(float4*)&Bs[brow][bcol] = bv;
    __syncthreads();
#pragma unroll
    for (int kk = 0; kk < 16; kk++) {
      float a[4];
#pragma unroll
      for (int i = 0; i < 4; i++) a[i] = As[tm * 4 + i][kk];
      float4 b = *(const float4*)&Bs[kk][tn * 4];
#pragma unroll
      for (int i = 0; i < 4; i++) {
        acc[i][0] = fmaf(a[i], b.x, acc[i][0]);
        acc[i][1] = fmaf(a[i], b.y, acc[i][1]);
        acc[i][2] = fmaf(a[i], b.z, acc[i][2]);
        acc[i][3] = fmaf(a[i], b.w, acc[i][3]);
      }
    }
    __syncthreads();
  }
  const int nl = bn * 64 + tn * 4;
  const int j = nl >> 9;
  const int ch = nl & 511;
  h16* dst = (j == 0) ? Kp : Vp;
#pragma unroll
  for (int i = 0; i < 4; i++) {
    int r = bm * 64 + tm * 4 + i;
    if (r < NPTOK) {
#pragma unroll
      for (int c = 0; c < 4; c++)
        dst[(size_t)r * 512 + ch + c] = (h16)(acc[i][c] + bias[512 + nl + c]);
    }
  }
}

// ---------------- Attention v3: S^T + fixed-max + shuffle-P --------------
// grid (144 win, 4 head, 2 qgroup), 4 waves; wave owns 2 q-tiles.
// S^T = K.Q^T via operand-swapped MFMA (k-dim in registers -> in-lane l sum).
// Fixed-max softmax (scores bounded), validity folded via 32-bit mask word.
// P^T->A-frag via 8 packed shuffles (no LDS roundtrip).
// Depth-2 prefetch: tok indices 2 steps ahead, K/V regs 1 step ahead.
__global__ __launch_bounds__(256, 3) void attn_kernel(
    const h16* __restrict__ Qh, const h16* __restrict__ KhU,
    const h16* __restrict__ VhU, const int* __restrict__ Tok,
    const int* __restrict__ WMask, h16* __restrict__ AOh)
{
  __shared__ h16 Ks[32 * 136];
  __shared__ h16 Vt[128 * 40];

  const int tid = threadIdx.x;
  const int lane = tid & 63;
  const int wv = tid >> 6;
  const int win = blockIdx.x;
  const int head = blockIdx.y;
  const int qg = blockIdx.z;
  const int wy = win / 12, wx = win % 12;
  const int col = lane & 15;
  const int quad = lane >> 4;
  const int* TokW = Tok + win * 1056;
  const int* WMaskW = WMask + win * 33;

  // ---- Q fragments for 2 tiles ----
  half8 qfrag[2][4];
  const int tile0 = qg * 8 + wv * 2;
#pragma unroll
  for (int tt = 0; tt < 2; tt++) {
    int qrow = (tile0 + tt) * 16 + col;
    if (qrow < 225) {
      int t = qrow / 45, pos = qrow % 45;
      int y = wy * 5 + pos / 9, x = wx * 9 + pos % 9;
      const h16* qsrc = Qh + (size_t)((t * 60 + y) * 108 + x) * CDIM + head * 128;
#pragma unroll
      for (int dc = 0; dc < 4; dc++)
        qfrag[tt][dc] = *(const half8*)(qsrc + dc * 32 + quad * 8);
    } else {
#pragma unroll
      for (int dc = 0; dc < 4; dc++)
#pragma unroll
        for (int jj = 0; jj < 8; jj++) qfrag[tt][dc][jj] = (h16)0.f;
    }
  }

  float4v O[2][8];
#pragma unroll
  for (int tt = 0; tt < 2; tt++)
#pragma unroll
    for (int i = 0; i < 8; i++) O[tt][i] = (float4v){0.f, 0.f, 0.f, 0.f};
  float lp[2] = {0.f, 0.f};

  // staging roles
  const int krow = tid >> 3, kseg = tid & 7;
  const int vrp = tid >> 4, vcg = tid & 15;
  const int kch = head * 128 + kseg * 16;
  const int vch = head * 128 + vcg * 8;
  const int vrot = (vcg & 3) * 4;
  const int rp = (vrp + vrot) & 15;

  // ---- prefetch pipeline ----
  int tokK[2], tokVa[2], tokVb[2];
  tokK[0]  = TokW[krow];          tokK[1]  = TokW[32 + krow];
  tokVa[0] = TokW[2 * vrp];       tokVa[1] = TokW[32 + 2 * vrp];
  tokVb[0] = TokW[2 * vrp + 1];   tokVb[1] = TokW[32 + 2 * vrp + 1];
  half8 k0c, k1c, vac, vbc, k0n, k1n, van, vbn;
  {
    const h16* ks = KhU + (size_t)tokK[0] * CDIM + kch;
    k0c = *(const half8*)ks;
    k1c = *(const half8*)(ks + 8);
    vac = *(const half8*)(VhU + (size_t)tokVa[0] * CDIM + vch);
    vbc = *(const half8*)(VhU + (size_t)tokVb[0] * CDIM + vch);
  }

  for (int step = 0; step < 33; ++step) {
    __syncthreads();   // previous step's LDS reads complete
    // ---- stage current regs into LDS ----
    *(half8*)&Ks[krow * 136 + kseg * 16] = k0c;
    *(half8*)&Ks[krow * 136 + kseg * 16 + 8] = k1c;
#pragma unroll
    for (int i = 0; i < 8; i++) {
      half2v w; w[0] = vac[i]; w[1] = vbc[i];
      *(half2v*)&Vt[(vcg * 8 + i) * 40 + rp * 2] = w;
    }
    // ---- issue next-step gathers (hidden under compute) ----
    if (step + 1 < 33) {
      const h16* ks = KhU + (size_t)tokK[(step + 1) & 1] * CDIM + kch;
      k0n = *(const half8*)ks;
      k1n = *(const half8*)(ks + 8);
      van = *(const half8*)(VhU + (size_t)tokVa[(step + 1) & 1] * CDIM + vch);
      vbn = *(const half8*)(VhU + (size_t)tokVb[(step + 1) & 1] * CDIM + vch);
      if (step + 2 < 33) {
        tokK[step & 1]  = TokW[(step + 2) * 32 + krow];
        tokVa[step & 1] = TokW[(step + 2) * 32 + 2 * vrp];
        tokVb[step & 1] = TokW[(step + 2) * 32 + 2 * vrp + 1];
      }
    }
    __syncthreads();

    const int mask = WMaskW[step];

    // ---- S^T = K.Q^T (operand-swapped) ----
    float4v s0[2] = {{0.f,0.f,0.f,0.f},{0.f,0.f,0.f,0.f}};
    float4v s1[2] = {{0.f,0.f,0.f,0.f},{0.f,0.f,0.f,0.f}};
#pragma unroll
    for (int dc = 0; dc < 4; dc++) {
      half8 a0 = *(const half8*)&Ks[col * 136 + dc * 32 + quad * 8];
      half8 a1 = *(const half8*)&Ks[(col + 16) * 136 + dc * 32 + quad * 8];
#pragma unroll
      for (int tt = 0; tt < 2; tt++) {
        s0[tt] = __builtin_amdgcn_mfma_f32_16x16x32_f16(a0, qfrag[tt][dc], s0[tt], 0, 0, 0);
        s1[tt] = __builtin_amdgcn_mfma_f32_16x16x32_f16(a1, qfrag[tt][dc], s1[tt], 0, 0, 0);
      }
    }

    // ---- fixed-max softmax + P^T -> A-frag via shuffles ----
    half8 pfrag[2];
    const int srcA = (((quad << 1) & 3) << 4) | col;
    const int srcB = ((((quad << 1) + 1) & 3) << 4) | col;
    const bool hi = quad >= 2;
#pragma unroll
    for (int tt = 0; tt < 2; tt++) {
      float pm0[4], pm1[4];
#pragma unroll
      for (int i = 0; i < 4; i++) {
        int r = quad * 4 + i;
        float e0 = __expf(s0[tt][i] * SCALE);
        float e1 = __expf(s1[tt][i] * SCALE);
        pm0[i] = ((mask >> r) & 1) ? e0 : 0.f;
        pm1[i] = ((mask >> (16 + r)) & 1) ? e1 : 0.f;
        lp[tt] += pm0[i] + pm1[i];
      }
      float g00 = __builtin_bit_cast(float, __builtin_amdgcn_cvt_pkrtz(pm0[0], pm0[1]));
      float g01 = __builtin_bit_cast(float, __builtin_amdgcn_cvt_pkrtz(pm0[2], pm0[3]));
      float g10 = __builtin_bit_cast(float, __builtin_amdgcn_cvt_pkrtz(pm1[0], pm1[1]));
      float g11 = __builtin_bit_cast(float, __builtin_amdgcn_cvt_pkrtz(pm1[2], pm1[3]));
      float a0 = __shfl(g00, srcA), a1 = __shfl(g01, srcA);
      float a2 = __shfl(g00, srcB), a3 = __shfl(g01, srcB);
      float b0 = __shfl(g10, srcA), b1 = __shfl(g11, srcA);
      float b2 = __shfl(g10, srcB), b3 = __shfl(g11, srcB);
      float4v pf;
      pf[0] = hi ? b0 : a0;
      pf[1] = hi ? b1 : a1;
      pf[2] = hi ? b2 : a2;
      pf[3] = hi ? b3 : a3;
      pfrag[tt] = __builtin_bit_cast(half8, pf);
    }

    // ---- O += P V (shared V fragments, single b128 each) ----
#pragma unroll
    for (int dt = 0; dt < 8; dt++) {
      int ch = dt * 16 + col;
      int g4 = ((dt * 2 + (col >> 3)) & 3) * 4;
      int x0 = (quad * 4 + g4) & 15;
      half8 vf = *(const half8*)&Vt[ch * 40 + x0 * 2];
#pragma unroll
      for (int tt = 0; tt < 2; tt++)
        O[tt][dt] = __builtin_amdgcn_mfma_f32_16x16x32_f16(pfrag[tt], vf, O[tt][dt], 0, 0, 0);
    }

    k0c = k0n; k1c = k1n; vac = van; vbc = vbn;
  }

  // ---- epilogue: deferred l reduction + store ----
#pragma unroll
  for (int tt = 0; tt < 2; tt++) {
    float l_all = lp[tt];
    l_all += __shfl_xor(l_all, 16);
    l_all += __shfl_xor(l_all, 32);
#pragma unroll
    for (int i = 0; i < 4; i++) {
      int qr = (tile0 + tt) * 16 + quad * 4 + i;
      if (qr < 225) {
        float invl = __builtin_amdgcn_rcpf(__shfl(l_all, quad * 4 + i));
        h16* dst = AOh + ((size_t)win * 225 + qr) * CDIM + head * 128 + col;
#pragma unroll
        for (int dt = 0; dt < 8; dt++)
          dst[dt * 16] = (h16)(O[tt][dt][i] * invl);
      }
    }
  }
}

extern "C" void kernel_launch(void* const* d_in, const int* in_sizes, int n_in,
                              void* d_out, int out_size, void* d_ws, size_t ws_size,
                              hipStream_t stream) {
  const float* x0    = (const float*)d_in[0];
  const float* x1    = (const float*)d_in[1];
  const float* Wqkv  = (const float*)d_in[2];
  const float* bqkv  = (const float*)d_in[3];
  const float* Wproj = (const float*)d_in[4];
  const float* bproj = (const float*)d_in[5];
  float* out = (float*)d_out;

  const size_t NU = (size_t)(NTOK + 1 + NPTOK);   // unified K/V row count
  h16* Qh   = (h16*)d_ws;
  h16* KhU  = Qh + (size_t)NTOK * CDIM;
  h16* VhU  = KhU + NU * CDIM;
  h16* AOh  = VhU + NU * CDIM;
  h16* Wqkvt  = AOh + (size_t)NTOK * CDIM;        // 1536 x 512
  h16* Wprojt = Wqkvt + (size_t)1536 * 512;       // 512 x 512
  int* Tok    = (int*)(Wprojt + (size_t)512 * 512);  // 144 x 1056
  int* WMaskP = Tok + (size_t)144 * 1056;            // 144 x 33

  build_tok<<<144, 256, 0, stream>>>(Tok, WMaskP);
  zero_rows<<<1, 256, 0, stream>>>(KhU, VhU);
  transpose_cvt<<<dim3(48, 16), 256, 0, stream>>>(Wqkv, Wqkvt, 512, 1536);
  transpose_cvt<<<dim3(16, 16), 256, 0, stream>>>(Wproj, Wprojt, 512, 512);

  gemm_qkv_mfma<<<dim3(254, 12), 256, 0, stream>>>(x0, Wqkvt, bqkv, Qh, KhU, VhU);
  gemm_pooled<<<dim3(12, 16), 256, 0, stream>>>(x1, Wqkv, bqkv,
                                                KhU + (size_t)PROW * CDIM,
                                                VhU + (size_t)PROW * CDIM);
  attn_kernel<<<dim3(144, 4, 2), 256, 0, stream>>>(Qh, KhU, VhU, Tok, WMaskP, AOh);
  gemm_proj_mfma<<<dim3(254, 4), 256, 0, stream>>>(AOh, Wprojt, bproj, out);
}